// Round 6
// baseline (4518.899 us; speedup 1.0000x reference)
//
#include <hip/hip_runtime.h>
#include <stdint.h>

// The np reference was generated with XLA-CPU-style FP contraction: the LIF
// recurrence MUST be fmaf(alpha, v, i) — verified bit-exact in round 4's
// designed experiment (separate mul/add flips 1-2 of 26.2M l1 decisions).
#pragma clang fp contract(off)

#define BB 128
#define TT 100
#define NN 2048
#define OO 512
#define DLY 10

#define ALPHA_F 0.90483741803595952f
#define DEC_F   0.95122942450071403f
#define OMD_F   0.048770575499285966f
#define A_P 1e-4f
#define A_M 1e-4f
#define THRV 0.02f
#define INVB 0.0078125f   // 1/128 exact

// ---- workspace layout (bytes) ----
#define OFF_MASK   ((size_t)0)          // u64 [BB][TT][32]  l1 spike bitmasks
#define OFF_HWT    ((size_t)3276800)    // f32 [NN][OO]      hw transposed
#define OFF_IEWT   ((size_t)7471104)    // f32 [OO][OO]      iew transposed, diag-masked
#define OFF_TR1    ((size_t)8519680)    // f32 [BB][NN]
#define OFF_TR2    ((size_t)9568256)    // f32 [BB][OO]
#define OFF_TRI    ((size_t)9830400)    // f32 [BB][OO]
#define OFF_V2     ((size_t)10092544)   // f32 [BB][OO]
#define OFF_VI     ((size_t)10354688)   // f32 [BB][OO]
#define OFF_BUF    ((size_t)10616832)   // f32 [BB][DLY][OO]
#define OFF_EIWD   ((size_t)13238272)   // f32 [OO]          eiw diagonal
#define OFF_ML2    ((size_t)13240320)   // f32 [2][OO]  sum_b l2 (exact ints)
#define OFF_MINH   ((size_t)13244416)   // f32 [2][OO]  sum_b inh
#define OFF_MTR2S  ((size_t)13248512)   // f32 [2][OO]  mean(tr2) state
#define OFF_MTRIS  ((size_t)13252608)   // f32 [2][OO]  mean(tri) state
#define OFF_COLS   ((size_t)13256704)   // f32 [2][OO]  column sums of iewT
#define OFF_FLAGS  ((size_t)13260800)   // u32 [4]: 0=anyL2spike
#define WS_NEED    ((size_t)13260816)

#define PTRS(ws) \
  unsigned long long* mask = (unsigned long long*)((ws) + OFF_MASK); \
  float* hwT  = (float*)((ws) + OFF_HWT);  \
  float* iewT = (float*)((ws) + OFF_IEWT); \
  float* tr1  = (float*)((ws) + OFF_TR1);  \
  float* tr2  = (float*)((ws) + OFF_TR2);  \
  float* tri  = (float*)((ws) + OFF_TRI);  \
  float* v2   = (float*)((ws) + OFF_V2);   \
  float* vi   = (float*)((ws) + OFF_VI);   \
  float* buf  = (float*)((ws) + OFF_BUF);  \
  float* eiwd = (float*)((ws) + OFF_EIWD); \
  float* ml2  = (float*)((ws) + OFF_ML2);  \
  float* minh = (float*)((ws) + OFF_MINH); \
  float* m2s  = (float*)((ws) + OFF_MTR2S);\
  float* m3s  = (float*)((ws) + OFF_MTRIS);\
  float* cols = (float*)((ws) + OFF_COLS); \
  unsigned* flags = (unsigned*)((ws) + OFF_FLAGS); \
  (void)mask;(void)hwT;(void)iewT;(void)tr1;(void)tr2;(void)tri;(void)v2;(void)vi; \
  (void)buf;(void)eiwd;(void)ml2;(void)minh;(void)m2s;(void)m3s;(void)cols;(void)flags;

// bit i of a 16-bit value -> bit 4i of a 64-bit value
__device__ __forceinline__ unsigned long long spread16(unsigned long long v) {
  v &= 0xFFFFull;
  v = (v | (v << 24)) & 0x000000FF000000FFull;
  v = (v | (v << 12)) & 0x000F000F000F000Full;
  v = (v | (v << 6))  & 0x0303030303030303ull;
  v = (v | (v << 3))  & 0x1111111111111111ull;
  return v;
}

// Zero the flag words before kA (ws arrives poisoned 0xAA).
__global__ void kZ(uint8_t* __restrict__ ws) {
  PTRS(ws);
  if (threadIdx.x < 4) flags[threadIdx.x] = 0u;
}

// ---------------------------------------------------------------------------
// Kernel A: l1/v1 path, 4 n's per thread, float4 loads/stores. Mask words
// assembled from 4 ballots + bit spread. Blocks [0,256): workers (b = bx>>1,
// half = bx&1). Blocks [256,1280): workspace init.
// ---------------------------------------------------------------------------
__global__ __launch_bounds__(256) void kA(
    const float* __restrict__ x, const float* __restrict__ w_in,
    const float* __restrict__ hid, const float* __restrict__ eiw_in,
    const float* __restrict__ iew_in, float* __restrict__ out,
    uint8_t* __restrict__ ws)
{
#pragma clang fp contract(off)
  const int bx = blockIdx.x, tid = threadIdx.x;
  PTRS(ws);

  if (bx < 256) {
    const int b = bx >> 1;
    const int half = bx & 1;
    const int n0 = half * 1024 + tid * 4;           // 4 consecutive n per thread
    const int wave = tid >> 6, lane = tid & 63;
    const int base_word = half * 16 + wave * 4;
    float wd0 = w_in[(size_t)(n0+0) * NN + (n0+0)];
    float wd1 = w_in[(size_t)(n0+1) * NN + (n0+1)];
    float wd2 = w_in[(size_t)(n0+2) * NN + (n0+2)];
    float wd3 = w_in[(size_t)(n0+3) * NN + (n0+3)];
    const float4* xp4 = (const float4*)(x + ((size_t)b * TT) * NN + n0);
    float4* op4 = (float4*)(out + ((size_t)b * TT) * NN + n0);
    float v0 = 0.f, v1 = 0.f, v2r = 0.f, v3 = 0.f;
    for (int t = 0; t < TT; ++t) {
      float4 xv = xp4[(size_t)t * (NN/4)];
      v0 = fmaf(ALPHA_F, v0, wd0 * xv.x);   // bit-exact vs np ref (round-4 exp)
      v1 = fmaf(ALPHA_F, v1, wd1 * xv.y);
      v2r = fmaf(ALPHA_F, v2r, wd2 * xv.z);
      v3 = fmaf(ALPHA_F, v3, wd3 * xv.w);
      bool s0 = (v0 > THRV), s1 = (v1 > THRV), s2 = (v2r > THRV), s3 = (v3 > THRV);
      op4[(size_t)t * (NN/4)] = make_float4(s0?1.f:0.f, s1?1.f:0.f, s2?1.f:0.f, s3?1.f:0.f);
      if (s0) v0 = 0.f; if (s1) v1 = 0.f; if (s2) v2r = 0.f; if (s3) v3 = 0.f;
      unsigned long long b0 = __ballot(s0), b1 = __ballot(s1);
      unsigned long long b2 = __ballot(s2), b3 = __ballot(s3);
      if (lane < 4) {
        int sh = lane * 16;
        unsigned long long w = spread16(b0 >> sh) | (spread16(b1 >> sh) << 1)
                             | (spread16(b2 >> sh) << 2) | (spread16(b3 >> sh) << 3);
        mask[((size_t)b * TT + t) * 32 + base_word + lane] = w;
      }
    }
  } else {
    const int idx = (bx - 256) * 256 + tid;         // 0..262143
    #pragma unroll
    for (int k = 0; k < 4; ++k) {                   // hwT[n][q] = hid[q][n]
      int e = idx + k * 262144;
      int n = e & (NN - 1);
      int q = e >> 11;
      hwT[(size_t)n * OO + q] = hid[(size_t)q * NN + n];
    }
    { int p = idx >> 9, q = idx & (OO - 1);         // iewT[p][q] = iew[q][p], diag 0
      iewT[idx] = (p == q) ? 0.f : iew_in[(size_t)q * OO + p]; }
    tr1[idx] = 0.f;
    if (idx < BB * OO) { tr2[idx]=0.f; tri[idx]=0.f; v2[idx]=0.f; vi[idx]=0.f; }
    #pragma unroll
    for (int k = 0; k < 3; ++k) { int e = idx + k * 262144; if (e < BB*DLY*OO) buf[e]=0.f; }
    if (idx < OO) eiwd[idx] = eiw_in[(size_t)idx * OO + idx];
    if (idx < 2*OO) { ml2[idx]=0.f; minh[idx]=0.f; m2s[idx]=0.f; m3s[idx]=0.f; }
    if (idx < OO) {                                 // cols slot0 = masked row-sums of iew_in
      float sacc = 0.f;
      for (int p = 0; p < OO; ++p) if (p != idx) sacc += iew_in[(size_t)idx * OO + p];
      cols[idx] = sacc; cols[OO + idx] = 0.f;
    }
  }
}

// ---------------------------------------------------------------------------
// K1(t): blocks [0,128): per-batch O-path. Atomic-free ballot/prefix
//        compaction for spike list and buf-zero list. blocks [128,256): tr1.
// ---------------------------------------------------------------------------
__global__ __launch_bounds__(512) void kStep1(
    const int* __restrict__ train_p, float* __restrict__ out,
    uint8_t* __restrict__ ws, int t)
{
#pragma clang fp contract(off)
  const int bx = blockIdx.x, tid = threadIdx.x;
  const int s = t & 1, tm = t % DLY;
  PTRS(ws);
  const int train = *train_p;
  const int se = train ? s : 0;   // eval: cols never cycles, use slot 0

  if (bx < BB) {
    __shared__ unsigned long long sm[32];
    __shared__ unsigned long long zm[8];
    __shared__ int wpre[32];
    __shared__ int zpre[8];
    __shared__ int wtot, ztot;
    __shared__ int sidx[NN];
    __shared__ short szer[OO];
    const int b = bx, q = tid;
    const int wv = tid >> 6, ln = tid & 63;

    // load mask words + per-word popcount + exclusive scan (wave 0, registers)
    if (tid < 32) {
      unsigned long long myw = mask[((size_t)b * TT + t) * 32 + tid];
      sm[tid] = myw;
      int pc = __popcll(myw);
      int incl = pc;
      #pragma unroll
      for (int d = 1; d < 32; d <<= 1) {
        int o = __shfl_up(incl, d);
        if (tid >= d) incl += o;
      }
      wpre[tid] = incl - pc;
      if (tid == 31) wtot = incl;
    }
    float bv = buf[((size_t)b * DLY + tm) * OO + q];
    float c = cols[se * OO + q];
    { unsigned long long bz = __ballot(bv == 0.f);
      if (ln == 0) zm[wv] = bz; }
    if (train && bx == 0) {                         // cycle double-buffered slots
      cols[(s ^ 1) * OO + q] = 0.f;
      ml2 [(s ^ 1) * OO + q] = 0.f;
      minh[(s ^ 1) * OO + q] = 0.f;
    }
    const int anyc = __syncthreads_or(c != 0.f ? 1 : 0);   // barrier 1
    if (tid < 8) {
      int pc = __popcll(zm[tid]);
      int incl = pc;
      #pragma unroll
      for (int d = 1; d < 8; d <<= 1) {
        int o = __shfl_up(incl, d);
        if (tid >= d) incl += o;
      }
      zpre[tid] = incl - pc;
      if (tid == 7) ztot = incl;
    }
    __syncthreads();                                        // barrier 2
    // scatter: spike list (4 n per thread), zero list (1 q per thread)
    #pragma unroll
    for (int k = 0; k < 4; ++k) {
      int n = (k << 9) + tid;
      unsigned long long m = sm[n >> 6];
      if ((m >> (n & 63)) & 1ull) {
        int pos = wpre[n >> 6] + __popcll(m & ((1ull << (n & 63)) - 1ull));
        sidx[pos] = n;
      }
    }
    if (bv == 0.f) {
      int pos = zpre[wv] + __popcll(zm[wv] & ((1ull << ln) - 1ull));
      szer[pos] = (short)q;
    }
    __syncthreads();                                        // barrier 3

    // l1v[b,q] = sum over spiking n of hwT[n][q]  (order-free robust path)
    float l1v = 0.f;
    { const int cnt = wtot;
      int k = 0;
      for (; k + 8 <= cnt; k += 8) {
        float h0=hwT[(size_t)sidx[k  ]*OO+q], h1=hwT[(size_t)sidx[k+1]*OO+q];
        float h2=hwT[(size_t)sidx[k+2]*OO+q], h3=hwT[(size_t)sidx[k+3]*OO+q];
        float h4=hwT[(size_t)sidx[k+4]*OO+q], h5=hwT[(size_t)sidx[k+5]*OO+q];
        float h6=hwT[(size_t)sidx[k+6]*OO+q], h7=hwT[(size_t)sidx[k+7]*OO+q];
        l1v += h0; l1v += h1; l1v += h2; l1v += h3;
        l1v += h4; l1v += h5; l1v += h6; l1v += h7;
      }
      for (; k < cnt; ++k) l1v += hwT[(size_t)sidx[k]*OO+q];
    }
    if (!train) l1v = 0.2f * l1v;
    // inh_out = colsum - sum over buf==0 rows (exactly 0 while iew == 0)
    float inh_o = 0.f;
    if (anyc) {
      float acc = c; const int zc = ztot;
      int k = 0;
      for (; k + 8 <= zc; k += 8) {
        acc -= iewT[(size_t)szer[k  ]*OO+q]; acc -= iewT[(size_t)szer[k+1]*OO+q];
        acc -= iewT[(size_t)szer[k+2]*OO+q]; acc -= iewT[(size_t)szer[k+3]*OO+q];
        acc -= iewT[(size_t)szer[k+4]*OO+q]; acc -= iewT[(size_t)szer[k+5]*OO+q];
        acc -= iewT[(size_t)szer[k+6]*OO+q]; acc -= iewT[(size_t)szer[k+7]*OO+q];
      }
      for (; k < zc; ++k) acc -= iewT[(size_t)szer[k]*OO+q];
      inh_o = acc;
    }
    // l2 neuron (FMA recurrence; margins robust)
    const int bq = b * OO + q;
    float i2  = l1v - inh_o;
    float v2v = fmaf(ALPHA_F, v2[bq], i2);
    bool l2 = (v2v > THRV);
    v2[bq] = l2 ? 0.f : v2v;
    out[(size_t)BB*TT*NN + ((size_t)b * TT + t) * OO + q] = l2 ? 1.f : 0.f;
    // inh neuron: inh_in = l2 * eiw_diag[q] (exact; eiw diag-masked each step)
    float ii  = l2 ? eiwd[q] : 0.f;
    float viv = fmaf(ALPHA_F, vi[bq], ii);
    bool ih = (viv > THRV);
    vi[bq] = ih ? 0.f : viv;
    buf[((size_t)b * DLY + tm) * OO + q] = ih ? 1.f : 0.f;
    if (train) {
      float l2f = l2 ? 1.f : 0.f, ihf = ih ? 1.f : 0.f;
      float d2 = DEC_F * tr2[bq]; tr2[bq] = d2 + OMD_F * l2f;
      float d3 = DEC_F * tri[bq]; tri[bq] = d3 + OMD_F * ihf;
      if (l2) { atomicAdd(&ml2[s * OO + q], 1.f); flags[0] = 1u; }  // exact int sums
      if (ih) { atomicAdd(&minh[s * OO + q], 1.f); }
    }
  } else {
    // tr1 update for batch b (sole writer; K2 reads afterwards)
    const int b = bx - BB;
    if (train) {
      const float* lp = out + ((size_t)b * TT + t) * NN;
      float* tp = tr1 + (size_t)b * NN;
      #pragma unroll
      for (int k = 0; k < 4; ++k) {
        int n = (k << 9) + tid;
        float d = DEC_F * tp[n];
        tp[n] = d + OMD_F * lp[n];
      }
    }
  }
}

// ---------------------------------------------------------------------------
// K2(t): blocks [0,256): hw (O x N) rank-128 STDP update, tiled 64x64.
//        blocks [256,320): iew (O x O) update + next-step column sums.
//        block 320: eiw diagonal + mean-state cycling.
// ---------------------------------------------------------------------------
__global__ __launch_bounds__(256) void kStep2(
    const int* __restrict__ train_p, uint8_t* __restrict__ ws, int t)
{
#pragma clang fp contract(off)
  const int bx = blockIdx.x, tid = threadIdx.x;
  const int s = t & 1;
  PTRS(ws);
  if (!*train_p) return;

  if (bx < 320) {
    if (!flags[0]) return;                 // no l2 spike yet => tr2 == 0 => no-op
    const bool isHW = (bx < 256);
    const int e  = isHW ? bx : (bx - 256);
    const int pt = e >> 3, qt = e & 7;
    __shared__ __align__(16) float s1[BB * 64];
    __shared__ __align__(16) float s2[BB * 64];
    const float* Apre = isHW ? tr1 : tri;  // pre-trace slab
    const int preStride = isHW ? NN : OO;
    #pragma unroll
    for (int it = 0; it < 8; ++it) {       // float4 staging: 2048 float4 units
      int e4 = it * 256 + tid;
      int b = e4 >> 4, i4 = e4 & 15;
      ((float4*)s1)[e4] = *(const float4*)&Apre[(size_t)b * preStride + pt * 64 + i4 * 4];
      ((float4*)s2)[e4] = *(const float4*)&tr2[b * OO + qt * 64 + i4 * 4];
    }
    __syncthreads();
    const int tp = tid >> 4, tq = tid & 15;
    float acc[4][4] = {{0.f,0.f,0.f,0.f},{0.f,0.f,0.f,0.f},{0.f,0.f,0.f,0.f},{0.f,0.f,0.f,0.f}};
    #pragma unroll 4
    for (int b = 0; b < BB; ++b) {
      float4 av = *(const float4*)&s1[b * 64 + tp * 4];
      float4 cv = *(const float4*)&s2[b * 64 + tq * 4];
      acc[0][0] = fmaf(av.x, cv.x, acc[0][0]);
      acc[0][1] = fmaf(av.x, cv.y, acc[0][1]);
      acc[0][2] = fmaf(av.x, cv.z, acc[0][2]);
      acc[0][3] = fmaf(av.x, cv.w, acc[0][3]);
      acc[1][0] = fmaf(av.y, cv.x, acc[1][0]);
      acc[1][1] = fmaf(av.y, cv.y, acc[1][1]);
      acc[1][2] = fmaf(av.y, cv.z, acc[1][2]);
      acc[1][3] = fmaf(av.y, cv.w, acc[1][3]);
      acc[2][0] = fmaf(av.z, cv.x, acc[2][0]);
      acc[2][1] = fmaf(av.z, cv.y, acc[2][1]);
      acc[2][2] = fmaf(av.z, cv.z, acc[2][2]);
      acc[2][3] = fmaf(av.z, cv.w, acc[2][3]);
      acc[3][0] = fmaf(av.w, cv.x, acc[3][0]);
      acc[3][1] = fmaf(av.w, cv.y, acc[3][1]);
      acc[3][2] = fmaf(av.w, cv.z, acc[3][2]);
      acc[3][3] = fmaf(av.w, cv.w, acc[3][3]);
    }
    float mq[4];
    #pragma unroll
    for (int j = 0; j < 4; ++j) {          // mean(tr2_t) via exact binary-spike recurrence
      int q = qt * 64 + tq * 4 + j;
      mq[j] = DEC_F * m2s[s * OO + q] + OMD_F * (ml2[s * OO + q] * INVB);
    }
    if (isHW) {
      #pragma unroll
      for (int i = 0; i < 4; ++i) {
        size_t p = (size_t)(pt * 64 + tp * 4 + i);
        float4* hp4 = (float4*)&hwT[p * OO + qt * 64 + tq * 4];
        float4 o = *hp4;
        o.x = o.x + (A_P * (acc[i][0] * INVB) - A_M * o.x * mq[0]);
        o.y = o.y + (A_P * (acc[i][1] * INVB) - A_M * o.y * mq[1]);
        o.z = o.z + (A_P * (acc[i][2] * INVB) - A_M * o.z * mq[2]);
        o.w = o.w + (A_P * (acc[i][3] * INVB) - A_M * o.w * mq[3]);
        *hp4 = o;
      }
    } else {
      float csum[4] = {0.f,0.f,0.f,0.f};
      #pragma unroll
      for (int i = 0; i < 4; ++i) {
        int p = pt * 64 + tp * 4 + i;
        float4* wp4 = (float4*)&iewT[(size_t)p * OO + qt * 64 + tq * 4];
        float4 o = *wp4;
        float nv[4];
        #pragma unroll
        for (int j = 0; j < 4; ++j) {
          int q = qt * 64 + tq * 4 + j;
          float old = (&o.x)[j];
          nv[j] = (p == q) ? 0.f
                           : (old + (A_P * (acc[i][j] * INVB) - A_M * old * mq[j]));
          csum[j] += nv[j];
        }
        *wp4 = make_float4(nv[0], nv[1], nv[2], nv[3]);
      }
      #pragma unroll
      for (int j = 0; j < 4; ++j)
        atomicAdd(&cols[(s ^ 1) * OO + (qt * 64 + tq * 4 + j)], csum[j]);
    }
  } else {
    // block 320: eiw diagonal + mean-state slot cycling (runs every step)
    for (int k = 0; k < 2; ++k) {
      int q = k * 256 + tid;
      float m2v = DEC_F * m2s[s*OO+q] + OMD_F * (ml2[s*OO+q] * INVB);
      float m3v = DEC_F * m3s[s*OO+q] + OMD_F * (minh[s*OO+q] * INVB);
      m2s[(s^1)*OO+q] = m2v;
      m3s[(s^1)*OO+q] = m3v;
      float hd = 0.f;
      for (int b = 0; b < BB; ++b) hd = fmaf(tri[b*OO+q], tr2[b*OO+q], hd);
      hd *= INVB;
      float old = eiwd[q];
      eiwd[q] = old + (A_P * hd - A_M * old * m3v);
    }
  }
}

extern "C" void kernel_launch(void* const* d_in, const int* in_sizes, int n_in,
                              void* d_out, int out_size, void* d_ws, size_t ws_size,
                              hipStream_t stream) {
  const float* x     = (const float*)d_in[0];
  const float* w_in  = (const float*)d_in[1];
  const float* hid   = (const float*)d_in[2];
  const float* eiw   = (const float*)d_in[3];
  const float* iew   = (const float*)d_in[4];
  const int*   train = (const int*)d_in[5];
  float* out = (float*)d_out;
  uint8_t* ws = (uint8_t*)d_ws;
  (void)in_sizes; (void)n_in; (void)out_size; (void)ws_size;

  hipLaunchKernelGGL(kZ, dim3(1), dim3(64), 0, stream, ws);
  hipLaunchKernelGGL(kA, dim3(1280), dim3(256), 0, stream, x, w_in, hid, eiw, iew, out, ws);
  for (int t = 0; t < TT; ++t) {
    hipLaunchKernelGGL(kStep1, dim3(256), dim3(512), 0, stream, train, out, ws, t);
    hipLaunchKernelGGL(kStep2, dim3(321), dim3(256), 0, stream, train, ws, t);
  }
}